// Round 1
// baseline (67.189 us; speedup 1.0000x reference)
//
#include <hip/hip_runtime.h>

// OverlapAdd: x (16, 512, 80, 81) f32 -> out (16, 512, 3240) f32
// p = 40, two_p = 80, n_chunks = 81 (chunk 80 unused; tail reuses chunk 79).
//
// Per (b,f) row, with j = t/40, r = t%40:
//   j == 0      : out[t] = x[r, 0]
//   1 <= j <= 79: out[t] = x[r, j] + x[r+40, j-1]
//   j == 80     : out[t] = x[r, 79] + x[r+40, 79]
//
// One block per (b,f) row: stage 80x81 tile in LDS (coalesced float4 loads),
// write coalesced. LDS read stride 81 -> bank stride 17 (coprime 32): no conflicts.

#define NCH 81          // n_chunks
#define CS  80          // chunk_size = 2p
#define P   40          // shift
#define NF  3240        // n_frames
#define ROW_IN (CS * NCH)   // 6480 floats per (b,f) row
#define NROWS (16 * 512)    // 8192

__global__ __launch_bounds__(256)
void OverlapAdd_60155311948306_kernel(const float* __restrict__ x,
                                      float* __restrict__ out) {
    const int row = blockIdx.x;                       // b*512 + f
    const float* __restrict__ xr  = x   + (size_t)row * ROW_IN;
    float*       __restrict__ outr = out + (size_t)row * NF;

    __shared__ float tile[ROW_IN];                    // 25.9 KB

    // Coalesced staging: 6480 floats = 1620 float4
    const float4* __restrict__ x4 = (const float4*)xr;
    float4* t4 = (float4*)tile;
    for (int i = threadIdx.x; i < ROW_IN / 4; i += 256) {
        t4[i] = x4[i];
    }
    __syncthreads();

    // Coalesced output: each thread one frame per iteration
    for (int t = threadIdx.x; t < NF; t += 256) {
        const int j = t / P;          // 0..80 (compiler: magic-mul)
        const int r = t - j * P;      // 0..39

        const int ja = (j < CS - 1) ? j : (CS - 1);          // min(j, 79)
        float v = tile[r * NCH + ja];
        if (j > 0) {
            const int jb = (j - 1 < CS - 1) ? (j - 1) : (CS - 1);  // min(j-1, 79)
            v += tile[(r + P) * NCH + jb];
        }
        outr[t] = v;
    }
}

extern "C" void kernel_launch(void* const* d_in, const int* in_sizes, int n_in,
                              void* d_out, int out_size, void* d_ws, size_t ws_size,
                              hipStream_t stream) {
    const float* x = (const float*)d_in[0];
    float* out = (float*)d_out;
    OverlapAdd_60155311948306_kernel<<<dim3(NROWS), dim3(256), 0, stream>>>(x, out);
}

// Round 2
// 55.482 us; speedup vs baseline: 1.2110x; 1.2110x over previous
//
#include <hip/hip_runtime.h>

// OverlapAdd: x (16, 512, 80, 81) f32 -> out (16, 512, 3240) f32
// p = 40, two_p = 80, n_chunks = 81 (chunk 80 unused; tail reuses chunk 79).
//
// Per (b,f) row, with j = t/40, r = t%40:
//   j == 0      : out[t] = x[r, 0]
//   1 <= j <= 79: out[t] = x[r, j] + x[r+40, j-1]
//   j == 80     : out[t] = x[r, 79] + x[r+40, 79]
//
// One block per (b,f) row. Stage the 80x81 tile in LDS via
// global_load_lds width=16 (no VGPR round trip), then emit float4 outputs:
// a 4-aligned frame group never crosses a j-band (40 % 4 == 0), so each
// group is 1 div + 8 ds_read_b32 + 4 fma + 1 global_store_dwordx4.
// LDS read bank stride: r-step of 4 rows = 324 floats -> bank stride 4,
// max 2-way aliasing across a wave (free).

#define NCH 81              // n_chunks
#define CS  80              // chunk_size = 2p
#define P   40              // shift
#define NF  3240            // n_frames
#define ROW_IN (CS * NCH)   // 6480 floats per (b,f) row
#define NROWS (16 * 512)    // 8192
#define NVEC4 (ROW_IN / 4)  // 1620 float4 per row
#define NG    (NF / 4)      // 810 output float4 groups per row

#define GLD_LDS16(g, l)                                                        \
    __builtin_amdgcn_global_load_lds(                                          \
        (const __attribute__((address_space(1))) void*)(g),                    \
        (__attribute__((address_space(3))) void*)(l), 16, 0, 0)

__global__ __launch_bounds__(256)
void OverlapAdd_60155311948306_kernel(const float* __restrict__ x,
                                      float* __restrict__ out) {
    const int row = blockIdx.x;                         // b*512 + f
    const float* __restrict__ xr   = x   + (size_t)row * ROW_IN;
    float*       __restrict__ outr = out + (size_t)row * NF;

    __shared__ float tile[ROW_IN];                      // 25.9 KB
    const int tid = threadIdx.x;

    // --- Stage 1620 float4s. 6 full-wave rounds of 256 lanes = 1536;
    //     remainder 84 via safe reg path (partial wave).
#pragma unroll
    for (int k = 0; k < 6; ++k) {
        const int i = k * 256 + tid;                    // float4 index
        GLD_LDS16(xr + 4 * i, tile + 4 * i);
    }
    if (tid < NVEC4 - 6 * 256) {                        // 84 threads
        const int i = 6 * 256 + tid;
        const float4 v = ((const float4*)xr)[i];
        ((float4*)tile)[i] = v;
    }
    __syncthreads();

    // --- Output: 810 float4 groups, 3 full rounds + 42-thread tail.
    float4* __restrict__ out4 = (float4*)outr;

    auto emit = [&](int g) {
        const int j  = g / 10;                          // 0..80 (magic-mul)
        const int rb = (g - j * 10) * 4;                // 0,4,...,36

        const int ja = (j < CS - 1) ? j : (CS - 1);     // min(j, 79)
        const int jb = (j <= 1) ? 0 : ((j - 1 < CS - 1) ? (j - 1) : (CS - 1));
        const float s = (j > 0) ? 1.0f : 0.0f;          // branchless j==0 band

        const float* t1 = tile + rb * NCH + ja;
        const float* t2 = tile + (rb + P) * NCH + jb;

        float4 v;
        v.x = fmaf(s, t2[0 * NCH], t1[0 * NCH]);
        v.y = fmaf(s, t2[1 * NCH], t1[1 * NCH]);
        v.z = fmaf(s, t2[2 * NCH], t1[2 * NCH]);
        v.w = fmaf(s, t2[3 * NCH], t1[3 * NCH]);
        out4[g] = v;
    };

    emit(tid);
    emit(tid + 256);
    emit(tid + 512);
    if (tid < NG - 3 * 256) emit(tid + 768);            // 42 threads
}

extern "C" void kernel_launch(void* const* d_in, const int* in_sizes, int n_in,
                              void* d_out, int out_size, void* d_ws, size_t ws_size,
                              hipStream_t stream) {
    const float* x = (const float*)d_in[0];
    float* out = (float*)d_out;
    OverlapAdd_60155311948306_kernel<<<dim3(NROWS), dim3(256), 0, stream>>>(x, out);
}

// Round 4
// 50.069 us; speedup vs baseline: 1.3419x; 1.1081x over previous
//
#include <hip/hip_runtime.h>

// OverlapAdd: x (16, 512, 80, 81) f32 -> out (16, 512, 3240) f32
// p = 40, two_p = 80, n_chunks = 81 (chunk 80 unused; tail reuses chunk 79).
//
// Per (b,f) row, with j = t/40, r = t%40:
//   j == 0      : out[t] = x[r, 0]
//   1 <= j <= 79: out[t] = x[r, j] + x[r+40, j-1]
//   j == 80     : out[t] = x[r, 79] + x[r+40, 79]
//
// One block per (b,f) row. Stage the 80x81 tile in LDS via
// global_load_lds width=16, then emit float4 outputs (a 4-aligned frame
// group never crosses a j-band since 40 % 4 == 0).
//
// Round-4: non-temporal output stores via native ext_vector_type
// (__builtin_nontemporal_store rejects HIP_vector_type float4).
// Output (106 MB) is write-once/never-read; keeping it out of L2/L3
// lets the 212 MB input stay Infinity-Cache-resident across replays.

#define NCH 81              // n_chunks
#define CS  80              // chunk_size = 2p
#define P   40              // shift
#define NF  3240            // n_frames
#define ROW_IN (CS * NCH)   // 6480 floats per (b,f) row
#define NROWS (16 * 512)    // 8192
#define NVEC4 (ROW_IN / 4)  // 1620 float4 per row
#define NG    (NF / 4)      // 810 output float4 groups per row

typedef float f32x4 __attribute__((ext_vector_type(4)));

#define GLD_LDS16(g, l)                                                        \
    __builtin_amdgcn_global_load_lds(                                          \
        (const __attribute__((address_space(1))) void*)(g),                    \
        (__attribute__((address_space(3))) void*)(l), 16, 0, 0)

__global__ __launch_bounds__(256)
void OverlapAdd_60155311948306_kernel(const float* __restrict__ x,
                                      float* __restrict__ out) {
    const int row = blockIdx.x;                         // b*512 + f
    const float* __restrict__ xr   = x   + (size_t)row * ROW_IN;
    float*       __restrict__ outr = out + (size_t)row * NF;

    __shared__ float tile[ROW_IN];                      // 25.9 KB
    const int tid = threadIdx.x;

    // --- Stage 1620 float4s. 6 full-wave rounds of 256 lanes = 1536;
    //     remainder 84 via safe reg path (partial wave).
#pragma unroll
    for (int k = 0; k < 6; ++k) {
        const int i = k * 256 + tid;                    // float4 index
        GLD_LDS16(xr + 4 * i, tile + 4 * i);
    }
    if (tid < NVEC4 - 6 * 256) {                        // 84 threads
        const int i = 6 * 256 + tid;
        const f32x4 v = ((const f32x4*)xr)[i];
        ((f32x4*)tile)[i] = v;
    }
    __syncthreads();

    // --- Output: 810 float4 groups, 3 full rounds + 42-thread tail.
    f32x4* __restrict__ out4 = (f32x4*)outr;

    auto emit = [&](int g) {
        const int j  = g / 10;                          // 0..80 (magic-mul)
        const int rb = (g - j * 10) * 4;                // 0,4,...,36

        const int ja = (j < CS - 1) ? j : (CS - 1);     // min(j, 79)
        const int jb = (j <= 1) ? 0 : ((j - 1 < CS - 1) ? (j - 1) : (CS - 1));
        const float s = (j > 0) ? 1.0f : 0.0f;          // branchless j==0 band

        const float* t1 = tile + rb * NCH + ja;
        const float* t2 = tile + (rb + P) * NCH + jb;

        f32x4 v;
        v.x = fmaf(s, t2[0 * NCH], t1[0 * NCH]);
        v.y = fmaf(s, t2[1 * NCH], t1[1 * NCH]);
        v.z = fmaf(s, t2[2 * NCH], t1[2 * NCH]);
        v.w = fmaf(s, t2[3 * NCH], t1[3 * NCH]);
        __builtin_nontemporal_store(v, &out4[g]);       // nt: don't pollute L2/L3
    };

    emit(tid);
    emit(tid + 256);
    emit(tid + 512);
    if (tid < NG - 3 * 256) emit(tid + 768);            // 42 threads
}

extern "C" void kernel_launch(void* const* d_in, const int* in_sizes, int n_in,
                              void* d_out, int out_size, void* d_ws, size_t ws_size,
                              hipStream_t stream) {
    const float* x = (const float*)d_in[0];
    float* out = (float*)d_out;
    OverlapAdd_60155311948306_kernel<<<dim3(NROWS), dim3(256), 0, stream>>>(x, out);
}